// Round 3
// baseline (1685.928 us; speedup 1.0000x reference)
//
#include <hip/hip_runtime.h>
#include <hip/hip_bf16.h>
#include <cstddef>

// Problem constants
#define NBLK 8
#define DD   128
#define DI   256
#define NH   4
#define PP   64
#define NNs  32
#define CONVD 320
#define EE   580      // D_IN_PROJ
#define BB   2
#define LLEN 4096
#define ML   (BB*LLEN)   // 8192 rows
#define SEGS 64
#define TT   64          // SEGS*TT == LLEN

__device__ __forceinline__ float siluf(float x){ return x / (1.f + expf(-x)); }

__device__ __forceinline__ float waveReduceSum(float v){
#pragma unroll
    for (int off = 32; off > 0; off >>= 1) v += __shfl_xor(v, off, 64);
    return v;
}

// ---------------- LayerNorm: one wave per row of 128 ----------------
__global__ __launch_bounds__(256) void ln_kernel(const float* __restrict__ x,
                                                 const float* __restrict__ w,
                                                 const float* __restrict__ b,
                                                 float* __restrict__ out)
{
    int wave = threadIdx.x >> 6, lane = threadIdx.x & 63;
    int row = blockIdx.x * 4 + wave;            // grid = ML/4
    const float* xr = x + (size_t)row * DD;
    float2 v = *(const float2*)(xr + lane * 2);
    float s = waveReduceSum(v.x + v.y);
    float mu = s * (1.f / DD);
    float dx = v.x - mu, dy = v.y - mu;
    float q = waveReduceSum(dx*dx + dy*dy);
    float rstd = rsqrtf(q * (1.f / DD) + 1e-5f);
    int c = lane * 2;
    float* orow = out + (size_t)row * DD;
    orow[c]   = dx * rstd * w[c]   + b[c];
    orow[c+1] = dy * rstd * w[c+1] + b[c+1];
}

// ---------------- GEMM: C = A(M,K) * W(N,K)^T (+bias)(+resid), all f32 ----------------
__global__ __launch_bounds__(256) void gemm_k(const float* __restrict__ A,
                                              const float* __restrict__ W,
                                              const float* __restrict__ bias,
                                              const float* __restrict__ resid,
                                              float* __restrict__ C,
                                              int M, int Nn, int Kdim)
{
    __shared__ float As[16][68];
    __shared__ float Bs[16][68];
    const int tid = threadIdx.x;
    const int bm = blockIdx.y * 64;
    const int bn = blockIdx.x * 64;
    const int tx = tid & 15;          // -> n
    const int ty = tid >> 4;          // -> m
    const int lrow = tid >> 2;        // 0..63
    const int lk = (tid & 3) << 2;    // 0,4,8,12
    float acc[4][4] = {};

    for (int k0 = 0; k0 < Kdim; k0 += 16) {
        float4 av = *(const float4*)(A + (size_t)(bm + lrow) * Kdim + (k0 + lk));
        float4 wv = make_float4(0.f, 0.f, 0.f, 0.f);
        if (bn + lrow < Nn)
            wv = *(const float4*)(W + (size_t)(bn + lrow) * Kdim + (k0 + lk));
        As[lk+0][lrow] = av.x; As[lk+1][lrow] = av.y;
        As[lk+2][lrow] = av.z; As[lk+3][lrow] = av.w;
        Bs[lk+0][lrow] = wv.x; Bs[lk+1][lrow] = wv.y;
        Bs[lk+2][lrow] = wv.z; Bs[lk+3][lrow] = wv.w;
        __syncthreads();
#pragma unroll
        for (int kk = 0; kk < 16; kk++) {
            float4 a4 = *(const float4*)&As[kk][ty << 2];
            float4 b4 = *(const float4*)&Bs[kk][tx << 2];
            float a[4] = {a4.x, a4.y, a4.z, a4.w};
            float b[4] = {b4.x, b4.y, b4.z, b4.w};
#pragma unroll
            for (int i = 0; i < 4; i++)
#pragma unroll
                for (int j = 0; j < 4; j++)
                    acc[i][j] = fmaf(a[i], b[j], acc[i][j]);
        }
        __syncthreads();
    }

#pragma unroll
    for (int i = 0; i < 4; i++) {
        int m = bm + (ty << 2) + i;
#pragma unroll
        for (int j = 0; j < 4; j++) {
            int n = bn + (tx << 2) + j;
            if (n < Nn) {
                float v = acc[i][j];
                if (bias)  v += bias[n];
                if (resid) v += resid[(size_t)m * Nn + n];
                C[(size_t)m * Nn + n] = v;
            }
        }
    }
}

// ---------------- Depthwise causal conv K=4 + bias + SiLU ----------------
__global__ __launch_bounds__(256) void conv_kernel(const float* __restrict__ zx,
                                                   const float* __restrict__ cw,
                                                   const float* __restrict__ cb,
                                                   float* __restrict__ out)
{
    int idx = blockIdx.x * 256 + threadIdx.x;     // over ML*CONVD
    int c = idx % CONVD;
    int bl = idx / CONVD;
    int l = bl & (LLEN - 1);
    const float* wr = cw + c * 4;
    const float* base = zx + (size_t)bl * EE + DI + c;  // xBC section
    float s = wr[3] * base[0];
    if (l >= 1) s = fmaf(wr[2], base[-(ptrdiff_t)EE], s);
    if (l >= 2) s = fmaf(wr[1], base[-(ptrdiff_t)(2*EE)], s);
    if (l >= 3) s = fmaf(wr[0], base[-(ptrdiff_t)(3*EE)], s);
    s += cb[c];
    out[idx] = siluf(s);
}

// ---------------- dt = softplus(raw + dt_bias); dA = exp(-exp(A_log)*dt) ----------------
__global__ __launch_bounds__(256) void dt_kernel(const float* __restrict__ zx,
                                                 const float* __restrict__ dt_bias,
                                                 const float* __restrict__ A_log,
                                                 float* __restrict__ dtb,
                                                 float* __restrict__ dab)
{
    int idx = blockIdx.x * 256 + threadIdx.x;   // over ML*NH
    int h = idx & 3;
    int bl = idx >> 2;
    float v = zx[(size_t)bl * EE + (EE - NH) + h] + dt_bias[h];
    float dt = (v > 20.f) ? v : log1pf(expf(v));
    dtb[idx] = dt;
    dab[idx] = expf(-expf(A_log[h]) * dt);
}

// ---------------- Scan pass 1: per-segment local scan from zero ----------------
__global__ __launch_bounds__(64) void scan1(const float* __restrict__ conv,
                                            const float* __restrict__ dtb,
                                            const float* __restrict__ dab,
                                            float* __restrict__ seg,
                                            float* __restrict__ segsum)
{
    int bid = blockIdx.x;                 // (b*NH + h)*SEGS + s
    int s = bid % SEGS;
    int bh = bid / SEGS;
    int h = bh % NH;
    int b = bh / NH;
    int p = threadIdx.x;
    float hreg[NNs];
#pragma unroll
    for (int n = 0; n < NNs; n++) hreg[n] = 0.f;
    float sdt = 0.f;
    int t0 = s * TT;
    for (int t = 0; t < TT; t++) {
        int bl = b * LLEN + t0 + t;
        float dA = dab[bl * 4 + h];
        float dt = dtb[bl * 4 + h];
        float xv = conv[(size_t)bl * CONVD + h * PP + p];
        float dtx = dt * xv;
        const float4* Bp = (const float4*)(conv + (size_t)bl * CONVD + DI);
#pragma unroll
        for (int n4 = 0; n4 < 8; n4++) {
            float4 Bv = Bp[n4];
            hreg[n4*4+0] = fmaf(hreg[n4*4+0], dA, dtx * Bv.x);
            hreg[n4*4+1] = fmaf(hreg[n4*4+1], dA, dtx * Bv.y);
            hreg[n4*4+2] = fmaf(hreg[n4*4+2], dA, dtx * Bv.z);
            hreg[n4*4+3] = fmaf(hreg[n4*4+3], dA, dtx * Bv.w);
        }
        sdt += dt;
    }
    float* dst = seg + ((size_t)bid * PP + p) * NNs;
#pragma unroll
    for (int n4 = 0; n4 < 8; n4++)
        *(float4*)(dst + n4 * 4) = make_float4(hreg[n4*4+0], hreg[n4*4+1], hreg[n4*4+2], hreg[n4*4+3]);
    if (p == 0) segsum[bid] = sdt;
}

// ---------------- Scan pass 2: cross-segment combine (in-place: local-end -> start) ----------------
__global__ __launch_bounds__(256) void scan2(float* __restrict__ seg,
                                             const float* __restrict__ segsum,
                                             const float* __restrict__ A_log)
{
    int bh = blockIdx.x;          // 0..BB*NH-1
    int h = bh % NH;
    int slot = threadIdx.x;       // each handles 8 of 2048 state entries
    float negA = -expf(A_log[h]);
    float hs[8] = {0,0,0,0,0,0,0,0};
    for (int j = 0; j < SEGS; j++) {
        float Aj = expf(negA * segsum[bh * SEGS + j]);
        float* p = seg + ((size_t)(bh * SEGS + j)) * (PP * NNs) + slot * 8;
        float4 e0 = *(const float4*)p;
        float4 e1 = *(const float4*)(p + 4);
        *(float4*)p       = make_float4(hs[0], hs[1], hs[2], hs[3]);
        *(float4*)(p + 4) = make_float4(hs[4], hs[5], hs[6], hs[7]);
        hs[0] = fmaf(Aj, hs[0], e0.x); hs[1] = fmaf(Aj, hs[1], e0.y);
        hs[2] = fmaf(Aj, hs[2], e0.z); hs[3] = fmaf(Aj, hs[3], e0.w);
        hs[4] = fmaf(Aj, hs[4], e1.x); hs[5] = fmaf(Aj, hs[5], e1.y);
        hs[6] = fmaf(Aj, hs[6], e1.z); hs[7] = fmaf(Aj, hs[7], e1.w);
    }
}

// ---------------- Scan pass 3: re-scan with true initial state, emit y ----------------
__global__ __launch_bounds__(64) void scan3(const float* __restrict__ conv,
                                            const float* __restrict__ dtb,
                                            const float* __restrict__ dab,
                                            const float* __restrict__ seg,
                                            const float* __restrict__ Dp,
                                            float* __restrict__ y)
{
    int bid = blockIdx.x;
    int s = bid % SEGS;
    int bh = bid / SEGS;
    int h = bh % NH;
    int b = bh / NH;
    int p = threadIdx.x;
    float hreg[NNs];
    const float* src = seg + ((size_t)bid * PP + p) * NNs;
#pragma unroll
    for (int n4 = 0; n4 < 8; n4++) {
        float4 v = *(const float4*)(src + n4 * 4);
        hreg[n4*4+0] = v.x; hreg[n4*4+1] = v.y; hreg[n4*4+2] = v.z; hreg[n4*4+3] = v.w;
    }
    float dp = Dp[h];
    int t0 = s * TT;
    for (int t = 0; t < TT; t++) {
        int bl = b * LLEN + t0 + t;
        float dA = dab[bl * 4 + h];
        float dt = dtb[bl * 4 + h];
        float xv = conv[(size_t)bl * CONVD + h * PP + p];
        float dtx = dt * xv;
        const float4* Bp = (const float4*)(conv + (size_t)bl * CONVD + DI);
        const float4* Cp = (const float4*)(conv + (size_t)bl * CONVD + DI + NNs);
        float acc = 0.f;
#pragma unroll
        for (int n4 = 0; n4 < 8; n4++) {
            float4 Bv = Bp[n4];
            float4 Cv = Cp[n4];
            hreg[n4*4+0] = fmaf(hreg[n4*4+0], dA, dtx * Bv.x);
            hreg[n4*4+1] = fmaf(hreg[n4*4+1], dA, dtx * Bv.y);
            hreg[n4*4+2] = fmaf(hreg[n4*4+2], dA, dtx * Bv.z);
            hreg[n4*4+3] = fmaf(hreg[n4*4+3], dA, dtx * Bv.w);
            acc = fmaf(hreg[n4*4+0], Cv.x, acc);
            acc = fmaf(hreg[n4*4+1], Cv.y, acc);
            acc = fmaf(hreg[n4*4+2], Cv.z, acc);
            acc = fmaf(hreg[n4*4+3], Cv.w, acc);
        }
        y[(size_t)bl * DI + h * PP + p] = acc + dp * xv;
    }
}

// ---------------- y * silu(z), RMSNorm over 256, * rms_w ----------------
__global__ __launch_bounds__(256) void gaterms_kernel(const float* __restrict__ yin,
                                                      const float* __restrict__ zx,
                                                      const float* __restrict__ rmsw,
                                                      float* __restrict__ out)
{
    int wave = threadIdx.x >> 6, lane = threadIdx.x & 63;
    int row = blockIdx.x * 4 + wave;            // grid = ML/4
    float4 yv = *(const float4*)(yin + (size_t)row * DI + lane * 4);
    float4 zv = *(const float4*)(zx + (size_t)row * EE + lane * 4);
    yv.x *= siluf(zv.x); yv.y *= siluf(zv.y);
    yv.z *= siluf(zv.z); yv.w *= siluf(zv.w);
    float q = waveReduceSum(yv.x*yv.x + yv.y*yv.y + yv.z*yv.z + yv.w*yv.w);
    float r = rsqrtf(q * (1.f / DI) + 1e-5f);
    float4 wv = *(const float4*)(rmsw + lane * 4);
    float4 o = make_float4(yv.x*r*wv.x, yv.y*r*wv.y, yv.z*r*wv.z, yv.w*r*wv.w);
    *(float4*)(out + (size_t)row * DI + lane * 4) = o;
}

// ---------------- GLU: silu(x12[:256]) * x12[256:512] ----------------
__global__ __launch_bounds__(256) void glu_kernel(const float* __restrict__ x12,
                                                  float* __restrict__ g)
{
    int idx = blockIdx.x * 256 + threadIdx.x;   // over ML*64 (float4 granules)
    int row = idx >> 6;
    int c4 = (idx & 63) << 2;
    float4 a = *(const float4*)(x12 + (size_t)row * 512 + c4);
    float4 b = *(const float4*)(x12 + (size_t)row * 512 + 256 + c4);
    float4 o = make_float4(siluf(a.x)*b.x, siluf(a.y)*b.y, siluf(a.z)*b.z, siluf(a.w)*b.w);
    *(float4*)(g + (size_t)row * DI + c4) = o;
}

// ---------------- Final output copy (f32): [x ; residual] ----------------
__global__ __launch_bounds__(256) void outcopy_kernel(const float* __restrict__ x,
                                                      const float* __restrict__ xm,
                                                      float* __restrict__ out)
{
    int i = blockIdx.x * 256 + threadIdx.x;     // over ML*DD/4 granules
    float4 a = ((const float4*)x)[i];
    float4 b = ((const float4*)xm)[i];
    ((float4*)out)[i] = a;
    ((float4*)(out + (size_t)ML * DD))[i] = b;
}

extern "C" void kernel_launch(void* const* d_in, const int* in_sizes, int n_in,
                              void* d_out, int out_size, void* d_ws, size_t ws_size,
                              hipStream_t stream)
{
    (void)in_sizes; (void)n_in; (void)out_size; (void)ws_size;
    const float* x_in      = (const float*)d_in[0];
    const float* ln1_w     = (const float*)d_in[2];
    const float* ln1_b     = (const float*)d_in[3];
    const float* ln2_w     = (const float*)d_in[4];
    const float* ln2_b     = (const float*)d_in[5];
    const float* fc1_w     = (const float*)d_in[6];
    const float* fc1_b     = (const float*)d_in[7];
    const float* fc2_w     = (const float*)d_in[8];
    const float* fc2_b     = (const float*)d_in[9];
    const float* in_proj_w = (const float*)d_in[10];
    const float* conv_w    = (const float*)d_in[11];
    const float* conv_b    = (const float*)d_in[12];
    const float* dt_bias   = (const float*)d_in[13];
    const float* A_log     = (const float*)d_in[14];
    const float* Dp        = (const float*)d_in[15];
    const float* rms_w     = (const float*)d_in[16];
    const float* out_proj_w= (const float*)d_in[17];

    float* ws = (float*)d_ws;
    size_t o = 0;
    float* bufX    = ws + o; o += (size_t)ML * DD;       // 1,048,576
    float* bufXm   = ws + o; o += (size_t)ML * DD;
    float* bufNorm = ws + o; o += (size_t)ML * DD;
    float* bufY    = ws + o; o += (size_t)ML * DI;       // 2,097,152
    float* bufG    = ws + o; o += (size_t)ML * DI;
    float* bufConv = ws + o; o += (size_t)ML * CONVD;    // 2,621,440
    float* bufDt   = ws + o; o += (size_t)ML * NH;
    float* bufDA   = ws + o; o += (size_t)ML * NH;
    float* bufSegA = ws + o; o += 512;
    float* bufSeg  = ws + o; o += (size_t)BB * NH * SEGS * PP * NNs;  // 1,048,576
    float* bufBig  = ws + o; o += (size_t)ML * EE;       // 4,751,360 (also x12: ML*512)

    hipMemcpyAsync(bufX, x_in, (size_t)ML * DD * sizeof(float),
                   hipMemcpyDeviceToDevice, stream);

    for (int i = 0; i < NBLK; i++) {
        const float* ln1wi = ln1_w + i * DD;
        const float* ln1bi = ln1_b + i * DD;
        const float* ln2wi = ln2_w + i * DD;
        const float* ln2bi = ln2_b + i * DD;
        const float* ipwi  = in_proj_w + (size_t)i * EE * DD;
        const float* cwi   = conv_w + (size_t)i * CONVD * 4;
        const float* cbi   = conv_b + (size_t)i * CONVD;
        const float* dtbi  = dt_bias + i * NH;
        const float* ali   = A_log + i * NH;
        const float* dpi   = Dp + i * NH;
        const float* rwi   = rms_w + (size_t)i * DI;
        const float* opwi  = out_proj_w + (size_t)i * DD * DI;
        const float* f1wi  = fc1_w + (size_t)i * 512 * DD;
        const float* f1bi  = fc1_b + (size_t)i * 512;
        const float* f2wi  = fc2_w + (size_t)i * DD * DI;
        const float* f2bi  = fc2_b + (size_t)i * DD;

        // x1 = LN1(x)
        ln_kernel<<<ML/4, 256, 0, stream>>>(bufX, ln1wi, ln1bi, bufNorm);
        // zxbcdt = x1 @ in_proj^T   (8192 x 580)
        gemm_k<<<dim3(10, ML/64), 256, 0, stream>>>(bufNorm, ipwi, nullptr, nullptr,
                                                    bufBig, ML, EE, DD);
        // conv + silu
        conv_kernel<<<(ML*CONVD)/256, 256, 0, stream>>>(bufBig, cwi, cbi, bufConv);
        // dt / dA
        dt_kernel<<<(ML*NH)/256, 256, 0, stream>>>(bufBig, dtbi, ali, bufDt, bufDA);
        // selective scan (3 passes)
        scan1<<<BB*NH*SEGS, 64, 0, stream>>>(bufConv, bufDt, bufDA, bufSeg, bufSegA);
        scan2<<<BB*NH, 256, 0, stream>>>(bufSeg, bufSegA, ali);
        scan3<<<BB*NH*SEGS, 64, 0, stream>>>(bufConv, bufDt, bufDA, bufSeg, dpi, bufY);
        // gated RMS norm
        gaterms_kernel<<<ML/4, 256, 0, stream>>>(bufY, bufBig, rwi, bufG);
        // x_m = x + ynorm @ out_proj^T
        gemm_k<<<dim3(2, ML/64), 256, 0, stream>>>(bufG, opwi, nullptr, bufX,
                                                   bufXm, ML, DD, DI);
        // x2 = LN2(x_m)
        ln_kernel<<<ML/4, 256, 0, stream>>>(bufXm, ln2wi, ln2bi, bufNorm);
        // x12 = x2 @ fc1^T + b   (8192 x 512)
        gemm_k<<<dim3(8, ML/64), 256, 0, stream>>>(bufNorm, f1wi, f1bi, nullptr,
                                                   bufBig, ML, 512, DD);
        // g = silu(x1p) * x2p
        glu_kernel<<<(ML*64)/256, 256, 0, stream>>>(bufBig, bufG);
        // x = x_m + g @ fc2^T + b
        gemm_k<<<dim3(2, ML/64), 256, 0, stream>>>(bufG, f2wi, f2bi, bufXm,
                                                   bufX, ML, DD, DI);
    }

    outcopy_kernel<<<(ML*DD)/1024, 256, 0, stream>>>(bufX, bufXm, (float*)d_out);
}

// Round 4
// 1533.654 us; speedup vs baseline: 1.0993x; 1.0993x over previous
//
#include <hip/hip_runtime.h>
#include <hip/hip_bf16.h>
#include <cstddef>

// Problem constants
#define NBLK 8
#define DD   128
#define DI   256
#define NH   4
#define PP   64
#define NNs  32
#define CONVD 320
#define EE   580      // D_IN_PROJ
#define BB   2
#define LLEN 4096
#define ML   (BB*LLEN)   // 8192 rows
#define SEGS 256
#define TT   16          // SEGS*TT == LLEN

__device__ __forceinline__ float siluf(float x){ return x / (1.f + expf(-x)); }

__device__ __forceinline__ float waveReduceSum(float v){
#pragma unroll
    for (int off = 32; off > 0; off >>= 1) v += __shfl_xor(v, off, 64);
    return v;
}

// ---------------- LayerNorm: one wave per row of 128 ----------------
__global__ __launch_bounds__(256) void ln_kernel(const float* __restrict__ x,
                                                 const float* __restrict__ w,
                                                 const float* __restrict__ b,
                                                 float* __restrict__ out)
{
    int wave = threadIdx.x >> 6, lane = threadIdx.x & 63;
    int row = blockIdx.x * 4 + wave;            // grid = ML/4
    const float* xr = x + (size_t)row * DD;
    float2 v = *(const float2*)(xr + lane * 2);
    float s = waveReduceSum(v.x + v.y);
    float mu = s * (1.f / DD);
    float dx = v.x - mu, dy = v.y - mu;
    float q = waveReduceSum(dx*dx + dy*dy);
    float rstd = rsqrtf(q * (1.f / DD) + 1e-5f);
    int c = lane * 2;
    float* orow = out + (size_t)row * DD;
    orow[c]   = dx * rstd * w[c]   + b[c];
    orow[c+1] = dy * rstd * w[c+1] + b[c+1];
}

// ---------------- GEMM: C = A(M,K) * W(N,K)^T (+bias)(+resid), all f32 ----------------
__global__ __launch_bounds__(256) void gemm_k(const float* __restrict__ A,
                                              const float* __restrict__ W,
                                              const float* __restrict__ bias,
                                              const float* __restrict__ resid,
                                              float* __restrict__ C,
                                              int M, int Nn, int Kdim)
{
    __shared__ float As[16][68];
    __shared__ float Bs[16][68];
    const int tid = threadIdx.x;
    const int bm = blockIdx.y * 64;
    const int bn = blockIdx.x * 64;
    const int tx = tid & 15;          // -> n
    const int ty = tid >> 4;          // -> m
    const int lrow = tid >> 2;        // 0..63
    const int lk = (tid & 3) << 2;    // 0,4,8,12
    float acc[4][4] = {};

    for (int k0 = 0; k0 < Kdim; k0 += 16) {
        float4 av = *(const float4*)(A + (size_t)(bm + lrow) * Kdim + (k0 + lk));
        float4 wv = make_float4(0.f, 0.f, 0.f, 0.f);
        if (bn + lrow < Nn)
            wv = *(const float4*)(W + (size_t)(bn + lrow) * Kdim + (k0 + lk));
        As[lk+0][lrow] = av.x; As[lk+1][lrow] = av.y;
        As[lk+2][lrow] = av.z; As[lk+3][lrow] = av.w;
        Bs[lk+0][lrow] = wv.x; Bs[lk+1][lrow] = wv.y;
        Bs[lk+2][lrow] = wv.z; Bs[lk+3][lrow] = wv.w;
        __syncthreads();
#pragma unroll
        for (int kk = 0; kk < 16; kk++) {
            float4 a4 = *(const float4*)&As[kk][ty << 2];
            float4 b4 = *(const float4*)&Bs[kk][tx << 2];
            float a[4] = {a4.x, a4.y, a4.z, a4.w};
            float b[4] = {b4.x, b4.y, b4.z, b4.w};
#pragma unroll
            for (int i = 0; i < 4; i++)
#pragma unroll
                for (int j = 0; j < 4; j++)
                    acc[i][j] = fmaf(a[i], b[j], acc[i][j]);
        }
        __syncthreads();
    }

#pragma unroll
    for (int i = 0; i < 4; i++) {
        int m = bm + (ty << 2) + i;
#pragma unroll
        for (int j = 0; j < 4; j++) {
            int n = bn + (tx << 2) + j;
            if (n < Nn) {
                float v = acc[i][j];
                if (bias)  v += bias[n];
                if (resid) v += resid[(size_t)m * Nn + n];
                C[(size_t)m * Nn + n] = v;
            }
        }
    }
}

// ---------------- Depthwise causal conv K=4 + bias + SiLU ----------------
__global__ __launch_bounds__(256) void conv_kernel(const float* __restrict__ zx,
                                                   const float* __restrict__ cw,
                                                   const float* __restrict__ cb,
                                                   float* __restrict__ out)
{
    int idx = blockIdx.x * 256 + threadIdx.x;     // over ML*CONVD
    int c = idx % CONVD;
    int bl = idx / CONVD;
    int l = bl & (LLEN - 1);
    const float* wr = cw + c * 4;
    const float* base = zx + (size_t)bl * EE + DI + c;  // xBC section
    float s = wr[3] * base[0];
    if (l >= 1) s = fmaf(wr[2], base[-(ptrdiff_t)EE], s);
    if (l >= 2) s = fmaf(wr[1], base[-(ptrdiff_t)(2*EE)], s);
    if (l >= 3) s = fmaf(wr[0], base[-(ptrdiff_t)(3*EE)], s);
    s += cb[c];
    out[idx] = siluf(s);
}

// ---------------- dt = softplus(raw + dt_bias); dA = exp(-exp(A_log)*dt) ----------------
__global__ __launch_bounds__(256) void dt_kernel(const float* __restrict__ zx,
                                                 const float* __restrict__ dt_bias,
                                                 const float* __restrict__ A_log,
                                                 float* __restrict__ dtb,
                                                 float* __restrict__ dab)
{
    int idx = blockIdx.x * 256 + threadIdx.x;   // over ML*NH
    int h = idx & 3;
    int bl = idx >> 2;
    float v = zx[(size_t)bl * EE + (EE - NH) + h] + dt_bias[h];
    float dt = (v > 20.f) ? v : log1pf(expf(v));
    dtb[idx] = dt;
    dab[idx] = expf(-expf(A_log[h]) * dt);
}

// ---------------- Scan pass 1: per-segment local scan from zero ----------------
__global__ __launch_bounds__(64) void scan1(const float* __restrict__ conv,
                                            const float* __restrict__ dtb,
                                            const float* __restrict__ dab,
                                            float* __restrict__ seg,
                                            float* __restrict__ segsum)
{
    int bid = blockIdx.x;                 // (b*NH + h)*SEGS + s
    int s = bid % SEGS;
    int bh = bid / SEGS;
    int h = bh % NH;
    int b = bh / NH;
    int p = threadIdx.x;
    float hreg[NNs];
#pragma unroll
    for (int n = 0; n < NNs; n++) hreg[n] = 0.f;
    float sdt = 0.f;
    int t0 = s * TT;
#pragma unroll 4
    for (int t = 0; t < TT; t++) {
        int bl = b * LLEN + t0 + t;
        float dA = dab[bl * 4 + h];
        float dt = dtb[bl * 4 + h];
        float xv = conv[(size_t)bl * CONVD + h * PP + p];
        float dtx = dt * xv;
        const float4* Bp = (const float4*)(conv + (size_t)bl * CONVD + DI);
#pragma unroll
        for (int n4 = 0; n4 < 8; n4++) {
            float4 Bv = Bp[n4];
            hreg[n4*4+0] = fmaf(hreg[n4*4+0], dA, dtx * Bv.x);
            hreg[n4*4+1] = fmaf(hreg[n4*4+1], dA, dtx * Bv.y);
            hreg[n4*4+2] = fmaf(hreg[n4*4+2], dA, dtx * Bv.z);
            hreg[n4*4+3] = fmaf(hreg[n4*4+3], dA, dtx * Bv.w);
        }
        sdt += dt;
    }
    float* dst = seg + ((size_t)bid * PP + p) * NNs;
#pragma unroll
    for (int n4 = 0; n4 < 8; n4++)
        *(float4*)(dst + n4 * 4) = make_float4(hreg[n4*4+0], hreg[n4*4+1], hreg[n4*4+2], hreg[n4*4+3]);
    if (p == 0) segsum[bid] = sdt;
}

// ---------------- Scan pass 2: cross-segment combine (in-place: local-end -> start) ----------------
// grid = BB*NH*8 blocks x 256 threads; each thread owns ONE of the 2048 state
// entries of one (b,h) and serially combines across all SEGS segments.
__global__ __launch_bounds__(256) void scan2(float* __restrict__ seg,
                                             const float* __restrict__ segsum,
                                             const float* __restrict__ A_log)
{
    int bh = blockIdx.x >> 3;             // 0..BB*NH-1
    int chunk = blockIdx.x & 7;
    int h = bh % NH;
    int entry = chunk * 256 + threadIdx.x;   // 0..2047
    float negA = -expf(A_log[h]);
    float hs = 0.f;
    const float* ss = segsum + bh * SEGS;
    float* base = seg + (size_t)bh * SEGS * (PP * NNs) + entry;
    for (int j = 0; j < SEGS; j++) {
        float Aj = expf(negA * ss[j]);
        float e = base[(size_t)j * (PP * NNs)];
        base[(size_t)j * (PP * NNs)] = hs;
        hs = fmaf(Aj, hs, e);
    }
}

// ---------------- Scan pass 3: re-scan with true initial state, emit y ----------------
__global__ __launch_bounds__(64) void scan3(const float* __restrict__ conv,
                                            const float* __restrict__ dtb,
                                            const float* __restrict__ dab,
                                            const float* __restrict__ seg,
                                            const float* __restrict__ Dp,
                                            float* __restrict__ y)
{
    int bid = blockIdx.x;
    int s = bid % SEGS;
    int bh = bid / SEGS;
    int h = bh % NH;
    int b = bh / NH;
    int p = threadIdx.x;
    float hreg[NNs];
    const float* src = seg + ((size_t)bid * PP + p) * NNs;
#pragma unroll
    for (int n4 = 0; n4 < 8; n4++) {
        float4 v = *(const float4*)(src + n4 * 4);
        hreg[n4*4+0] = v.x; hreg[n4*4+1] = v.y; hreg[n4*4+2] = v.z; hreg[n4*4+3] = v.w;
    }
    float dp = Dp[h];
    int t0 = s * TT;
#pragma unroll 4
    for (int t = 0; t < TT; t++) {
        int bl = b * LLEN + t0 + t;
        float dA = dab[bl * 4 + h];
        float dt = dtb[bl * 4 + h];
        float xv = conv[(size_t)bl * CONVD + h * PP + p];
        float dtx = dt * xv;
        const float4* Bp = (const float4*)(conv + (size_t)bl * CONVD + DI);
        const float4* Cp = (const float4*)(conv + (size_t)bl * CONVD + DI + NNs);
        float acc = 0.f;
#pragma unroll
        for (int n4 = 0; n4 < 8; n4++) {
            float4 Bv = Bp[n4];
            float4 Cv = Cp[n4];
            hreg[n4*4+0] = fmaf(hreg[n4*4+0], dA, dtx * Bv.x);
            hreg[n4*4+1] = fmaf(hreg[n4*4+1], dA, dtx * Bv.y);
            hreg[n4*4+2] = fmaf(hreg[n4*4+2], dA, dtx * Bv.z);
            hreg[n4*4+3] = fmaf(hreg[n4*4+3], dA, dtx * Bv.w);
            acc = fmaf(hreg[n4*4+0], Cv.x, acc);
            acc = fmaf(hreg[n4*4+1], Cv.y, acc);
            acc = fmaf(hreg[n4*4+2], Cv.z, acc);
            acc = fmaf(hreg[n4*4+3], Cv.w, acc);
        }
        y[(size_t)bl * DI + h * PP + p] = acc + dp * xv;
    }
}

// ---------------- y * silu(z), RMSNorm over 256, * rms_w ----------------
__global__ __launch_bounds__(256) void gaterms_kernel(const float* __restrict__ yin,
                                                      const float* __restrict__ zx,
                                                      const float* __restrict__ rmsw,
                                                      float* __restrict__ out)
{
    int wave = threadIdx.x >> 6, lane = threadIdx.x & 63;
    int row = blockIdx.x * 4 + wave;            // grid = ML/4
    float4 yv = *(const float4*)(yin + (size_t)row * DI + lane * 4);
    float4 zv = *(const float4*)(zx + (size_t)row * EE + lane * 4);
    yv.x *= siluf(zv.x); yv.y *= siluf(zv.y);
    yv.z *= siluf(zv.z); yv.w *= siluf(zv.w);
    float q = waveReduceSum(yv.x*yv.x + yv.y*yv.y + yv.z*yv.z + yv.w*yv.w);
    float r = rsqrtf(q * (1.f / DI) + 1e-5f);
    float4 wv = *(const float4*)(rmsw + lane * 4);
    float4 o = make_float4(yv.x*r*wv.x, yv.y*r*wv.y, yv.z*r*wv.z, yv.w*r*wv.w);
    *(float4*)(out + (size_t)row * DI + lane * 4) = o;
}

// ---------------- GLU: silu(x12[:256]) * x12[256:512] ----------------
__global__ __launch_bounds__(256) void glu_kernel(const float* __restrict__ x12,
                                                  float* __restrict__ g)
{
    int idx = blockIdx.x * 256 + threadIdx.x;   // over ML*64 (float4 granules)
    int row = idx >> 6;
    int c4 = (idx & 63) << 2;
    float4 a = *(const float4*)(x12 + (size_t)row * 512 + c4);
    float4 b = *(const float4*)(x12 + (size_t)row * 512 + 256 + c4);
    float4 o = make_float4(siluf(a.x)*b.x, siluf(a.y)*b.y, siluf(a.z)*b.z, siluf(a.w)*b.w);
    *(float4*)(g + (size_t)row * DI + c4) = o;
}

// ---------------- Final output copy (f32): [x ; residual] ----------------
__global__ __launch_bounds__(256) void outcopy_kernel(const float* __restrict__ x,
                                                      const float* __restrict__ xm,
                                                      float* __restrict__ out)
{
    int i = blockIdx.x * 256 + threadIdx.x;     // over ML*DD/4 granules
    float4 a = ((const float4*)x)[i];
    float4 b = ((const float4*)xm)[i];
    ((float4*)out)[i] = a;
    ((float4*)(out + (size_t)ML * DD))[i] = b;
}

extern "C" void kernel_launch(void* const* d_in, const int* in_sizes, int n_in,
                              void* d_out, int out_size, void* d_ws, size_t ws_size,
                              hipStream_t stream)
{
    (void)in_sizes; (void)n_in; (void)out_size; (void)ws_size;
    const float* x_in      = (const float*)d_in[0];
    const float* ln1_w     = (const float*)d_in[2];
    const float* ln1_b     = (const float*)d_in[3];
    const float* ln2_w     = (const float*)d_in[4];
    const float* ln2_b     = (const float*)d_in[5];
    const float* fc1_w     = (const float*)d_in[6];
    const float* fc1_b     = (const float*)d_in[7];
    const float* fc2_w     = (const float*)d_in[8];
    const float* fc2_b     = (const float*)d_in[9];
    const float* in_proj_w = (const float*)d_in[10];
    const float* conv_w    = (const float*)d_in[11];
    const float* conv_b    = (const float*)d_in[12];
    const float* dt_bias   = (const float*)d_in[13];
    const float* A_log     = (const float*)d_in[14];
    const float* Dp        = (const float*)d_in[15];
    const float* rms_w     = (const float*)d_in[16];
    const float* out_proj_w= (const float*)d_in[17];

    float* ws = (float*)d_ws;
    size_t o = 0;
    float* bufX    = ws + o; o += (size_t)ML * DD;       // 1,048,576
    float* bufXm   = ws + o; o += (size_t)ML * DD;
    float* bufNorm = ws + o; o += (size_t)ML * DD;
    float* bufY    = ws + o; o += (size_t)ML * DI;       // 2,097,152
    float* bufG    = ws + o; o += (size_t)ML * DI;
    float* bufConv = ws + o; o += (size_t)ML * CONVD;    // 2,621,440
    float* bufDt   = ws + o; o += (size_t)ML * NH;
    float* bufDA   = ws + o; o += (size_t)ML * NH;
    float* bufSegA = ws + o; o += (size_t)BB * NH * SEGS;
    float* bufSeg  = ws + o; o += (size_t)BB * NH * SEGS * PP * NNs;  // 4,194,304
    float* bufBig  = ws + o; o += (size_t)ML * EE;       // 4,751,360 (also x12: ML*512)

    hipMemcpyAsync(bufX, x_in, (size_t)ML * DD * sizeof(float),
                   hipMemcpyDeviceToDevice, stream);

    for (int i = 0; i < NBLK; i++) {
        const float* ln1wi = ln1_w + i * DD;
        const float* ln1bi = ln1_b + i * DD;
        const float* ln2wi = ln2_w + i * DD;
        const float* ln2bi = ln2_b + i * DD;
        const float* ipwi  = in_proj_w + (size_t)i * EE * DD;
        const float* cwi   = conv_w + (size_t)i * CONVD * 4;
        const float* cbi   = conv_b + (size_t)i * CONVD;
        const float* dtbi  = dt_bias + i * NH;
        const float* ali   = A_log + i * NH;
        const float* dpi   = Dp + i * NH;
        const float* rwi   = rms_w + (size_t)i * DI;
        const float* opwi  = out_proj_w + (size_t)i * DD * DI;
        const float* f1wi  = fc1_w + (size_t)i * 512 * DD;
        const float* f1bi  = fc1_b + (size_t)i * 512;
        const float* f2wi  = fc2_w + (size_t)i * DD * DI;
        const float* f2bi  = fc2_b + (size_t)i * DD;

        // x1 = LN1(x)
        ln_kernel<<<ML/4, 256, 0, stream>>>(bufX, ln1wi, ln1bi, bufNorm);
        // zxbcdt = x1 @ in_proj^T   (8192 x 580)
        gemm_k<<<dim3(10, ML/64), 256, 0, stream>>>(bufNorm, ipwi, nullptr, nullptr,
                                                    bufBig, ML, EE, DD);
        // conv + silu
        conv_kernel<<<(ML*CONVD)/256, 256, 0, stream>>>(bufBig, cwi, cbi, bufConv);
        // dt / dA
        dt_kernel<<<(ML*NH)/256, 256, 0, stream>>>(bufBig, dtbi, ali, bufDt, bufDA);
        // selective scan (3 passes)
        scan1<<<BB*NH*SEGS, 64, 0, stream>>>(bufConv, bufDt, bufDA, bufSeg, bufSegA);
        scan2<<<BB*NH*8, 256, 0, stream>>>(bufSeg, bufSegA, ali);
        scan3<<<BB*NH*SEGS, 64, 0, stream>>>(bufConv, bufDt, bufDA, bufSeg, dpi, bufY);
        // gated RMS norm
        gaterms_kernel<<<ML/4, 256, 0, stream>>>(bufY, bufBig, rwi, bufG);
        // x_m = x + ynorm @ out_proj^T
        gemm_k<<<dim3(2, ML/64), 256, 0, stream>>>(bufG, opwi, nullptr, bufX,
                                                   bufXm, ML, DD, DI);
        // x2 = LN2(x_m)
        ln_kernel<<<ML/4, 256, 0, stream>>>(bufXm, ln2wi, ln2bi, bufNorm);
        // x12 = x2 @ fc1^T + b   (8192 x 512)
        gemm_k<<<dim3(8, ML/64), 256, 0, stream>>>(bufNorm, f1wi, f1bi, nullptr,
                                                   bufBig, ML, 512, DD);
        // g = silu(x1p) * x2p
        glu_kernel<<<(ML*64)/256, 256, 0, stream>>>(bufBig, bufG);
        // x = x_m + g @ fc2^T + b
        gemm_k<<<dim3(2, ML/64), 256, 0, stream>>>(bufG, f2wi, f2bi, bufXm,
                                                   bufX, ML, DD, DI);
    }

    outcopy_kernel<<<(ML*DD)/1024, 256, 0, stream>>>(bufX, bufXm, (float*)d_out);
}

// Round 5
// 1069.934 us; speedup vs baseline: 1.5757x; 1.4334x over previous
//
#include <hip/hip_runtime.h>
#include <hip/hip_bf16.h>
#include <cstddef>

// Problem constants
#define NBLK 8
#define DD   128
#define DI   256
#define NH   4
#define PP   64
#define NNs  32
#define CONVD 320
#define EE   580      // D_IN_PROJ
#define BB   2
#define LLEN 4096
#define ML   (BB*LLEN)   // 8192 rows
#define SEGS 256
#define TT   16          // SEGS*TT == LLEN

typedef unsigned short u16;
typedef short bf16x8 __attribute__((ext_vector_type(8)));
typedef float f32x4 __attribute__((ext_vector_type(4)));

__device__ __forceinline__ float siluf(float x){ return x / (1.f + expf(-x)); }

__device__ __forceinline__ u16 f2b(float f){
    __hip_bfloat16 h = __float2bfloat16(f);   // RNE
    return *reinterpret_cast<u16*>(&h);
}

__device__ __forceinline__ float waveReduceSum(float v){
#pragma unroll
    for (int off = 32; off > 0; off >>= 1) v += __shfl_xor(v, off, 64);
    return v;
}

// ---------------- weights f32 -> bf16 (once per launch) ----------------
#define IPW_N (NBLK*EE*DD)          // 593920
#define OPW_N (NBLK*DD*DI)          // 262144
#define F1W_N (NBLK*512*DD)         // 524288
#define F2W_N (NBLK*DD*DI)          // 262144
#define CVT_TOT (IPW_N+OPW_N+F1W_N+F2W_N)   // 1642496 = 256*6416

__global__ __launch_bounds__(256) void cvt_weights(const float* __restrict__ ip,
                                                   const float* __restrict__ op,
                                                   const float* __restrict__ f1,
                                                   const float* __restrict__ f2,
                                                   u16* __restrict__ dip,
                                                   u16* __restrict__ dop,
                                                   u16* __restrict__ df1,
                                                   u16* __restrict__ df2)
{
    int i = blockIdx.x * 256 + threadIdx.x;
    if (i < IPW_N)                          dip[i] = f2b(ip[i]);
    else if (i < IPW_N + OPW_N)             dop[i - IPW_N] = f2b(op[i - IPW_N]);
    else if (i < IPW_N + OPW_N + F1W_N)     df1[i - IPW_N - OPW_N] = f2b(f1[i - IPW_N - OPW_N]);
    else                                    df2[i - IPW_N - OPW_N - F1W_N] = f2b(f2[i - IPW_N - OPW_N - F1W_N]);
}

// ---------------- LayerNorm: one wave per row of 128, bf16 out ----------------
__global__ __launch_bounds__(256) void ln_kernel(const float* __restrict__ x,
                                                 const float* __restrict__ w,
                                                 const float* __restrict__ b,
                                                 u16* __restrict__ out)
{
    int wave = threadIdx.x >> 6, lane = threadIdx.x & 63;
    int row = blockIdx.x * 4 + wave;            // grid = ML/4
    const float* xr = x + (size_t)row * DD;
    float2 v = *(const float2*)(xr + lane * 2);
    float s = waveReduceSum(v.x + v.y);
    float mu = s * (1.f / DD);
    float dx = v.x - mu, dy = v.y - mu;
    float q = waveReduceSum(dx*dx + dy*dy);
    float rstd = rsqrtf(q * (1.f / DD) + 1e-5f);
    int c = lane * 2;
    ushort2 o;
    o.x = f2b(dx * rstd * w[c]   + b[c]);
    o.y = f2b(dy * rstd * w[c+1] + b[c+1]);
    *(ushort2*)(out + (size_t)row * DD + c) = o;
}

// ---------------- MFMA GEMM: C_f32[M][N] = A_bf16[M][K] . W_bf16[N][K]^T ----------------
// BM=64, BN=64, BK=128; 256 threads = 4 waves; wave w computes rows w*16..w*16+15.
// LDS fragment-major layout: unit16B index (kk*4+sub)*64 + row   (kk: k/32, sub: (k%32)/8)
__global__ __launch_bounds__(256) void gemm_bf16(const u16* __restrict__ A,
                                                 const u16* __restrict__ W,
                                                 const float* __restrict__ bias,
                                                 const float* __restrict__ resid,
                                                 float* __restrict__ C,
                                                 int M, int Nn, int Kdim)
{
    __shared__ __align__(16) u16 Ash[64*128];   // 16 KB
    __shared__ __align__(16) u16 Wsh[64*128];   // 16 KB
    const int tid  = threadIdx.x;
    const int wave = tid >> 6, lane = tid & 63;
    const int l15  = lane & 15, quad = lane >> 4;
    const int bm = blockIdx.y * 64;
    const int bn = blockIdx.x * 64;
    const int arow = tid >> 2;      // staging row 0..63
    const int ak8  = tid & 3;       // staging k8 base

    f32x4 acc[4];
#pragma unroll
    for (int nt = 0; nt < 4; nt++) acc[nt] = (f32x4){0.f, 0.f, 0.f, 0.f};

    for (int k0 = 0; k0 < Kdim; k0 += 128) {
#pragma unroll
        for (int i = 0; i < 4; i++) {
            int k8 = ak8 + 4*i;                 // 0..15
            int kk = k8 >> 2, sub = k8 & 3;
            uint4 av = *(const uint4*)(A + (size_t)(bm + arow) * Kdim + k0 + k8*8);
            *(uint4*)&Ash[(((kk*4 + sub)*64) + arow) * 8] = av;
            uint4 wv = make_uint4(0u, 0u, 0u, 0u);
            if (bn + arow < Nn)
                wv = *(const uint4*)(W + (size_t)(bn + arow) * Kdim + k0 + k8*8);
            *(uint4*)&Wsh[(((kk*4 + sub)*64) + arow) * 8] = wv;
        }
        __syncthreads();
#pragma unroll
        for (int kk = 0; kk < 4; kk++) {
            bf16x8 af = *(const bf16x8*)&Ash[(((kk*4 + quad)*64) + wave*16 + l15) * 8];
#pragma unroll
            for (int nt = 0; nt < 4; nt++) {
                bf16x8 bfv = *(const bf16x8*)&Wsh[(((kk*4 + quad)*64) + nt*16 + l15) * 8];
                acc[nt] = __builtin_amdgcn_mfma_f32_16x16x32_bf16(af, bfv, acc[nt], 0, 0, 0);
            }
        }
        __syncthreads();
    }

#pragma unroll
    for (int nt = 0; nt < 4; nt++) {
        int n = bn + nt*16 + l15;
        if (n < Nn) {
            float bv = bias ? bias[n] : 0.f;
#pragma unroll
            for (int r = 0; r < 4; r++) {
                int m = bm + wave*16 + quad*4 + r;
                float v = acc[nt][r] + bv;
                if (resid) v += resid[(size_t)m * Nn + n];
                C[(size_t)m * Nn + n] = v;
            }
        }
    }
}

// ---------------- Depthwise causal conv K=4 + bias + SiLU, fused dt/dA ----------------
__global__ __launch_bounds__(256) void convdt_kernel(const float* __restrict__ zx,
                                                     const float* __restrict__ cw,
                                                     const float* __restrict__ cb,
                                                     const float* __restrict__ dt_bias,
                                                     const float* __restrict__ A_log,
                                                     float* __restrict__ out,
                                                     float* __restrict__ dtb,
                                                     float* __restrict__ dab)
{
    int idx = blockIdx.x * 256 + threadIdx.x;     // over ML*CONVD
    int c = idx % CONVD;
    int bl = idx / CONVD;
    int l = bl & (LLEN - 1);
    const float* wr = cw + c * 4;
    const float* base = zx + (size_t)bl * EE + DI + c;  // xBC section
    float s = wr[3] * base[0];
    if (l >= 1) s = fmaf(wr[2], base[-(ptrdiff_t)EE], s);
    if (l >= 2) s = fmaf(wr[1], base[-(ptrdiff_t)(2*EE)], s);
    if (l >= 3) s = fmaf(wr[0], base[-(ptrdiff_t)(3*EE)], s);
    s += cb[c];
    out[idx] = siluf(s);

    if (idx < ML * NH) {
        int h = idx & 3;
        int row = idx >> 2;
        float v = zx[(size_t)row * EE + (EE - NH) + h] + dt_bias[h];
        float dt = (v > 20.f) ? v : log1pf(expf(v));
        dtb[idx] = dt;
        dab[idx] = expf(-expf(A_log[h]) * dt);
    }
}

// ---------------- Scan pass 1: per-segment local scan (LDS-staged) ----------------
__global__ __launch_bounds__(64) void scan1(const float* __restrict__ conv,
                                            const float* __restrict__ dtb,
                                            const float* __restrict__ dab,
                                            float* __restrict__ seg,
                                            float* __restrict__ segsum)
{
    __shared__ float xs[TT*PP];
    __shared__ float Bsh[TT*NNs];
    __shared__ float dts[TT], das[TT];
    int bid = blockIdx.x;                 // (b*NH + h)*SEGS + s
    int s = bid % SEGS;
    int bh = bid / SEGS;
    int h = bh % NH;
    int b = bh / NH;
    int p = threadIdx.x;
    int row0 = b * LLEN + s * TT;
#pragma unroll
    for (int t = 0; t < TT; t++)
        xs[t*PP + p] = conv[(size_t)(row0 + t) * CONVD + h * PP + p];
#pragma unroll
    for (int tt = 0; tt < TT/2; tt++) {
        int t = tt*2 + (p >> 5);
        Bsh[t*NNs + (p & 31)] = conv[(size_t)(row0 + t) * CONVD + DI + (p & 31)];
    }
    if (p < TT) {
        dts[p] = dtb[(row0 + p) * NH + h];
        das[p] = dab[(row0 + p) * NH + h];
    }
    __syncthreads();

    float hreg[NNs];
#pragma unroll
    for (int n = 0; n < NNs; n++) hreg[n] = 0.f;
    float sdt = 0.f;
#pragma unroll
    for (int t = 0; t < TT; t++) {
        float dA = das[t];
        float dt = dts[t];
        float xv = xs[t*PP + p];
        float dtx = dt * xv;
#pragma unroll
        for (int n4 = 0; n4 < 8; n4++) {
            float4 Bv = *(const float4*)&Bsh[t*NNs + n4*4];
            hreg[n4*4+0] = fmaf(hreg[n4*4+0], dA, dtx * Bv.x);
            hreg[n4*4+1] = fmaf(hreg[n4*4+1], dA, dtx * Bv.y);
            hreg[n4*4+2] = fmaf(hreg[n4*4+2], dA, dtx * Bv.z);
            hreg[n4*4+3] = fmaf(hreg[n4*4+3], dA, dtx * Bv.w);
        }
        sdt += dt;
    }
    float* dst = seg + ((size_t)bid * PP + p) * NNs;
#pragma unroll
    for (int n4 = 0; n4 < 8; n4++)
        *(float4*)(dst + n4 * 4) = make_float4(hreg[n4*4+0], hreg[n4*4+1], hreg[n4*4+2], hreg[n4*4+3]);
    if (p == 0) segsum[bid] = sdt;
}

// ---------------- Scan pass 2: cross-segment combine (in-place) ----------------
__global__ __launch_bounds__(256) void scan2(float* __restrict__ seg,
                                             const float* __restrict__ segsum,
                                             const float* __restrict__ A_log)
{
    int bh = blockIdx.x >> 3;             // 0..BB*NH-1
    int chunk = blockIdx.x & 7;
    int h = bh % NH;
    int entry = chunk * 256 + threadIdx.x;   // 0..2047
    float negA = -expf(A_log[h]);
    float hs = 0.f;
    const float* ss = segsum + bh * SEGS;
    float* base = seg + (size_t)bh * SEGS * (PP * NNs) + entry;
    for (int j = 0; j < SEGS; j++) {
        float Aj = expf(negA * ss[j]);
        float e = base[(size_t)j * (PP * NNs)];
        base[(size_t)j * (PP * NNs)] = hs;
        hs = fmaf(Aj, hs, e);
    }
}

// ---------------- Scan pass 3: re-scan with true initial state, emit y (LDS-staged) ----------------
__global__ __launch_bounds__(64) void scan3(const float* __restrict__ conv,
                                            const float* __restrict__ dtb,
                                            const float* __restrict__ dab,
                                            const float* __restrict__ seg,
                                            const float* __restrict__ Dp,
                                            float* __restrict__ y)
{
    __shared__ float xs[TT*PP];
    __shared__ float Bsh[TT*NNs];
    __shared__ float Csh[TT*NNs];
    __shared__ float dts[TT], das[TT];
    int bid = blockIdx.x;
    int s = bid % SEGS;
    int bh = bid / SEGS;
    int h = bh % NH;
    int b = bh / NH;
    int p = threadIdx.x;
    int row0 = b * LLEN + s * TT;
#pragma unroll
    for (int t = 0; t < TT; t++)
        xs[t*PP + p] = conv[(size_t)(row0 + t) * CONVD + h * PP + p];
#pragma unroll
    for (int tt = 0; tt < TT/2; tt++) {
        int t = tt*2 + (p >> 5);
        Bsh[t*NNs + (p & 31)] = conv[(size_t)(row0 + t) * CONVD + DI + (p & 31)];
        Csh[t*NNs + (p & 31)] = conv[(size_t)(row0 + t) * CONVD + DI + NNs + (p & 31)];
    }
    if (p < TT) {
        dts[p] = dtb[(row0 + p) * NH + h];
        das[p] = dab[(row0 + p) * NH + h];
    }

    float hreg[NNs];
    const float* src = seg + ((size_t)bid * PP + p) * NNs;
#pragma unroll
    for (int n4 = 0; n4 < 8; n4++) {
        float4 v = *(const float4*)(src + n4 * 4);
        hreg[n4*4+0] = v.x; hreg[n4*4+1] = v.y; hreg[n4*4+2] = v.z; hreg[n4*4+3] = v.w;
    }
    float dp = Dp[h];
    __syncthreads();

#pragma unroll
    for (int t = 0; t < TT; t++) {
        float dA = das[t];
        float dt = dts[t];
        float xv = xs[t*PP + p];
        float dtx = dt * xv;
        float acc = 0.f;
#pragma unroll
        for (int n4 = 0; n4 < 8; n4++) {
            float4 Bv = *(const float4*)&Bsh[t*NNs + n4*4];
            float4 Cv = *(const float4*)&Csh[t*NNs + n4*4];
            hreg[n4*4+0] = fmaf(hreg[n4*4+0], dA, dtx * Bv.x);
            hreg[n4*4+1] = fmaf(hreg[n4*4+1], dA, dtx * Bv.y);
            hreg[n4*4+2] = fmaf(hreg[n4*4+2], dA, dtx * Bv.z);
            hreg[n4*4+3] = fmaf(hreg[n4*4+3], dA, dtx * Bv.w);
            acc = fmaf(hreg[n4*4+0], Cv.x, acc);
            acc = fmaf(hreg[n4*4+1], Cv.y, acc);
            acc = fmaf(hreg[n4*4+2], Cv.z, acc);
            acc = fmaf(hreg[n4*4+3], Cv.w, acc);
        }
        y[(size_t)(row0 + t) * DI + h * PP + p] = acc + dp * xv;
    }
}

// ---------------- y * silu(z), RMSNorm over 256, * rms_w -> bf16 ----------------
__global__ __launch_bounds__(256) void gaterms_kernel(const float* __restrict__ yin,
                                                      const float* __restrict__ zx,
                                                      const float* __restrict__ rmsw,
                                                      u16* __restrict__ out)
{
    int wave = threadIdx.x >> 6, lane = threadIdx.x & 63;
    int row = blockIdx.x * 4 + wave;            // grid = ML/4
    float4 yv = *(const float4*)(yin + (size_t)row * DI + lane * 4);
    float4 zv = *(const float4*)(zx + (size_t)row * EE + lane * 4);
    yv.x *= siluf(zv.x); yv.y *= siluf(zv.y);
    yv.z *= siluf(zv.z); yv.w *= siluf(zv.w);
    float q = waveReduceSum(yv.x*yv.x + yv.y*yv.y + yv.z*yv.z + yv.w*yv.w);
    float r = rsqrtf(q * (1.f / DI) + 1e-5f);
    float4 wv = *(const float4*)(rmsw + lane * 4);
    ushort4 o;
    o.x = f2b(yv.x*r*wv.x); o.y = f2b(yv.y*r*wv.y);
    o.z = f2b(yv.z*r*wv.z); o.w = f2b(yv.w*r*wv.w);
    *(ushort4*)(out + (size_t)row * DI + lane * 4) = o;
}

// ---------------- GLU: silu(x12[:256]) * x12[256:512] -> bf16 ----------------
__global__ __launch_bounds__(256) void glu_kernel(const float* __restrict__ x12,
                                                  u16* __restrict__ g)
{
    int idx = blockIdx.x * 256 + threadIdx.x;   // over ML*64 (float4 granules)
    int row = idx >> 6;
    int c4 = (idx & 63) << 2;
    float4 a = *(const float4*)(x12 + (size_t)row * 512 + c4);
    float4 b = *(const float4*)(x12 + (size_t)row * 512 + 256 + c4);
    ushort4 o;
    o.x = f2b(siluf(a.x)*b.x); o.y = f2b(siluf(a.y)*b.y);
    o.z = f2b(siluf(a.z)*b.z); o.w = f2b(siluf(a.w)*b.w);
    *(ushort4*)(g + (size_t)row * DI + c4) = o;
}

// ---------------- Final output copy (f32): [x ; residual] ----------------
__global__ __launch_bounds__(256) void outcopy_kernel(const float* __restrict__ x,
                                                      const float* __restrict__ xm,
                                                      float* __restrict__ out)
{
    int i = blockIdx.x * 256 + threadIdx.x;     // over ML*DD/4 granules
    float4 a = ((const float4*)x)[i];
    float4 b = ((const float4*)xm)[i];
    ((float4*)out)[i] = a;
    ((float4*)(out + (size_t)ML * DD))[i] = b;
}

extern "C" void kernel_launch(void* const* d_in, const int* in_sizes, int n_in,
                              void* d_out, int out_size, void* d_ws, size_t ws_size,
                              hipStream_t stream)
{
    (void)in_sizes; (void)n_in; (void)out_size; (void)ws_size;
    const float* x_in      = (const float*)d_in[0];
    const float* ln1_w     = (const float*)d_in[2];
    const float* ln1_b     = (const float*)d_in[3];
    const float* ln2_w     = (const float*)d_in[4];
    const float* ln2_b     = (const float*)d_in[5];
    const float* fc1_w     = (const float*)d_in[6];
    const float* fc1_b     = (const float*)d_in[7];
    const float* fc2_w     = (const float*)d_in[8];
    const float* fc2_b     = (const float*)d_in[9];
    const float* in_proj_w = (const float*)d_in[10];
    const float* conv_w    = (const float*)d_in[11];
    const float* conv_b    = (const float*)d_in[12];
    const float* dt_bias   = (const float*)d_in[13];
    const float* A_log     = (const float*)d_in[14];
    const float* Dp        = (const float*)d_in[15];
    const float* rms_w     = (const float*)d_in[16];
    const float* out_proj_w= (const float*)d_in[17];

    float* ws = (float*)d_ws;
    size_t o = 0;
    float* bufX    = ws + o; o += (size_t)ML * DD;       // f32
    float* bufXm   = ws + o; o += (size_t)ML * DD;       // f32
    float* bufY    = ws + o; o += (size_t)ML * DI;       // f32
    float* bufConv = ws + o; o += (size_t)ML * CONVD;    // f32
    float* bufDt   = ws + o; o += (size_t)ML * NH;
    float* bufDA   = ws + o; o += (size_t)ML * NH;
    float* bufSegA = ws + o; o += (size_t)BB * NH * SEGS;
    float* bufSeg  = ws + o; o += (size_t)BB * NH * SEGS * PP * NNs;  // f32
    float* bufBig  = ws + o; o += (size_t)ML * EE;       // f32 (also x12: ML*512)
    // bf16 regions (element counts halved vs floats; keep float-offset bookkeeping)
    u16* bufNormH = (u16*)(ws + o); o += (size_t)ML * DD / 2;
    u16* bufGH    = (u16*)(ws + o); o += (size_t)ML * DI / 2;
    u16* bufGluH  = (u16*)(ws + o); o += (size_t)ML * DI / 2;
    u16* wIpH     = (u16*)(ws + o); o += (IPW_N + 1) / 2;
    u16* wOpH     = (u16*)(ws + o); o += (OPW_N + 1) / 2;
    u16* wF1H     = (u16*)(ws + o); o += (F1W_N + 1) / 2;
    u16* wF2H     = (u16*)(ws + o); o += (F2W_N + 1) / 2;

    hipMemcpyAsync(bufX, x_in, (size_t)ML * DD * sizeof(float),
                   hipMemcpyDeviceToDevice, stream);
    cvt_weights<<<CVT_TOT/256, 256, 0, stream>>>(in_proj_w, out_proj_w, fc1_w, fc2_w,
                                                 wIpH, wOpH, wF1H, wF2H);

    for (int i = 0; i < NBLK; i++) {
        const float* ln1wi = ln1_w + i * DD;
        const float* ln1bi = ln1_b + i * DD;
        const float* ln2wi = ln2_w + i * DD;
        const float* ln2bi = ln2_b + i * DD;
        const float* cwi   = conv_w + (size_t)i * CONVD * 4;
        const float* cbi   = conv_b + (size_t)i * CONVD;
        const float* dtbi  = dt_bias + i * NH;
        const float* ali   = A_log + i * NH;
        const float* dpi   = Dp + i * NH;
        const float* rwi   = rms_w + (size_t)i * DI;
        const float* f1bi  = fc1_b + (size_t)i * 512;
        const float* f2bi  = fc2_b + (size_t)i * DD;
        const u16* ipwi = wIpH + (size_t)i * EE * DD;
        const u16* opwi = wOpH + (size_t)i * DD * DI;
        const u16* f1wi = wF1H + (size_t)i * 512 * DD;
        const u16* f2wi = wF2H + (size_t)i * DD * DI;

        // x1 = LN1(x) -> bf16
        ln_kernel<<<ML/4, 256, 0, stream>>>(bufX, ln1wi, ln1bi, bufNormH);
        // zxbcdt = x1 @ in_proj^T   (8192 x 580)
        gemm_bf16<<<dim3(10, ML/64), 256, 0, stream>>>(bufNormH, ipwi, nullptr, nullptr,
                                                       bufBig, ML, EE, DD);
        // conv + silu + dt/dA
        convdt_kernel<<<(ML*CONVD)/256, 256, 0, stream>>>(bufBig, cwi, cbi, dtbi, ali,
                                                          bufConv, bufDt, bufDA);
        // selective scan (3 passes)
        scan1<<<BB*NH*SEGS, 64, 0, stream>>>(bufConv, bufDt, bufDA, bufSeg, bufSegA);
        scan2<<<BB*NH*8, 256, 0, stream>>>(bufSeg, bufSegA, ali);
        scan3<<<BB*NH*SEGS, 64, 0, stream>>>(bufConv, bufDt, bufDA, bufSeg, dpi, bufY);
        // gated RMS norm -> bf16
        gaterms_kernel<<<ML/4, 256, 0, stream>>>(bufY, bufBig, rwi, bufGH);
        // x_m = x + ynorm @ out_proj^T
        gemm_bf16<<<dim3(2, ML/64), 256, 0, stream>>>(bufGH, opwi, nullptr, bufX,
                                                      bufXm, ML, DD, DI);
        // x2 = LN2(x_m) -> bf16
        ln_kernel<<<ML/4, 256, 0, stream>>>(bufXm, ln2wi, ln2bi, bufNormH);
        // x12 = x2 @ fc1^T + b   (8192 x 512)
        gemm_bf16<<<dim3(8, ML/64), 256, 0, stream>>>(bufNormH, f1wi, f1bi, nullptr,
                                                      bufBig, ML, 512, DD);
        // g = silu(x1p) * x2p -> bf16
        glu_kernel<<<(ML*64)/256, 256, 0, stream>>>(bufBig, bufGluH);
        // x = x_m + g @ fc2^T + b
        gemm_bf16<<<dim3(2, ML/64), 256, 0, stream>>>(bufGluH, f2wi, f2bi, bufXm,
                                                      bufX, ML, DD, DI);
    }

    outcopy_kernel<<<(ML*DD)/1024, 256, 0, stream>>>(bufX, bufXm, (float*)d_out);
}

// Round 6
// 1028.715 us; speedup vs baseline: 1.6389x; 1.0401x over previous
//
#include <hip/hip_runtime.h>
#include <hip/hip_bf16.h>
#include <cstddef>

// Problem constants
#define NBLK 8
#define DD   128
#define DI   256
#define NH   4
#define PP   64
#define NNs  32
#define CONVD 320
#define EE   580      // D_IN_PROJ
#define BB   2
#define LLEN 4096
#define ML   (BB*LLEN)   // 8192 rows
#define SEGS 128
#define TT   32          // SEGS*TT == LLEN
#define GPAD 264         // Gsh row stride (bf16) = 256 + 8

typedef unsigned short u16;
typedef short bf16x8 __attribute__((ext_vector_type(8)));
typedef float f32x4 __attribute__((ext_vector_type(4)));

__device__ __forceinline__ float siluf(float x){ return x / (1.f + expf(-x)); }

__device__ __forceinline__ u16 f2b(float f){
    __hip_bfloat16 h = __float2bfloat16(f);   // RNE
    return *reinterpret_cast<u16*>(&h);
}

// ---------------- weights f32 -> bf16 (once per launch) ----------------
#define IPW_N (NBLK*EE*DD)          // 593920
#define OPW_N (NBLK*DD*DI)          // 262144
#define F1W_N (NBLK*512*DD)         // 524288
#define F2W_N (NBLK*DD*DI)          // 262144
#define CVT_TOT (IPW_N+OPW_N+F1W_N+F2W_N)   // 1642496 = 256*6416

__global__ __launch_bounds__(256) void cvt_weights(const float* __restrict__ ip,
                                                   const float* __restrict__ op,
                                                   const float* __restrict__ f1,
                                                   const float* __restrict__ f2,
                                                   u16* __restrict__ dip,
                                                   u16* __restrict__ dop,
                                                   u16* __restrict__ df1,
                                                   u16* __restrict__ df2)
{
    int i = blockIdx.x * 256 + threadIdx.x;
    if (i < IPW_N)                          dip[i] = f2b(ip[i]);
    else if (i < IPW_N + OPW_N)             dop[i - IPW_N] = f2b(op[i - IPW_N]);
    else if (i < IPW_N + OPW_N + F1W_N)     df1[i - IPW_N - OPW_N] = f2b(f1[i - IPW_N - OPW_N]);
    else                                    df2[i - IPW_N - OPW_N - F1W_N] = f2b(f2[i - IPW_N - OPW_N - F1W_N]);
}

// ================= Fused LN1 + in_proj GEMM =================
// grid (10, ML/64); C[ML][EE] f32 = LN(X) @ W^T ; K=DD=128 (single tile)
__global__ __launch_bounds__(256) void inproj_ln_gemm(const float* __restrict__ X,
                                                      const float* __restrict__ lnw,
                                                      const float* __restrict__ lnb,
                                                      const u16* __restrict__ W,
                                                      float* __restrict__ C)
{
    __shared__ __align__(16) u16 Ash[64*128];
    __shared__ __align__(16) u16 Wsh[64*128];
    __shared__ float red[64][8];
    const int tid = threadIdx.x;
    const int wave = tid >> 6, lane = tid & 63;
    const int l15 = lane & 15, quad = lane >> 4;
    const int bm = blockIdx.y * 64;
    const int bn = blockIdx.x * 64;
    const int lrow = tid >> 2, sub = tid & 3;

    // W staging (single K tile)
#pragma unroll
    for (int i = 0; i < 4; i++) {
        int k8 = sub + 4*i;
        uint4 wv = make_uint4(0u,0u,0u,0u);
        if (bn + lrow < EE)
            wv = *(const uint4*)(W + (size_t)(bn + lrow) * DD + k8*8);
        *(uint4*)&Wsh[((size_t)k8*64 + lrow) * 8] = wv;
    }

    // LN prologue: row lrow, cols sub*32..+31
    const float* xr = X + (size_t)(bm + lrow) * DD + sub*32;
    float4 xv[8];
    float ps = 0.f, pq = 0.f;
#pragma unroll
    for (int i = 0; i < 8; i++) {
        xv[i] = *(const float4*)(xr + i*4);
        ps += xv[i].x + xv[i].y + xv[i].z + xv[i].w;
        pq += xv[i].x*xv[i].x + xv[i].y*xv[i].y + xv[i].z*xv[i].z + xv[i].w*xv[i].w;
    }
    red[lrow][sub] = ps; red[lrow][4+sub] = pq;
    __syncthreads();
    float s = red[lrow][0]+red[lrow][1]+red[lrow][2]+red[lrow][3];
    float q = red[lrow][4]+red[lrow][5]+red[lrow][6]+red[lrow][7];
    float mu = s * (1.f/DD);
    float rstd = rsqrtf(q*(1.f/DD) - mu*mu + 1e-5f);
#pragma unroll
    for (int i = 0; i < 4; i++) {
        float4 a0 = xv[2*i], a1 = xv[2*i+1];
        int c0 = sub*32 + i*8;
        u16 o[8];
        o[0] = f2b((a0.x-mu)*rstd*lnw[c0+0] + lnb[c0+0]);
        o[1] = f2b((a0.y-mu)*rstd*lnw[c0+1] + lnb[c0+1]);
        o[2] = f2b((a0.z-mu)*rstd*lnw[c0+2] + lnb[c0+2]);
        o[3] = f2b((a0.w-mu)*rstd*lnw[c0+3] + lnb[c0+3]);
        o[4] = f2b((a1.x-mu)*rstd*lnw[c0+4] + lnb[c0+4]);
        o[5] = f2b((a1.y-mu)*rstd*lnw[c0+5] + lnb[c0+5]);
        o[6] = f2b((a1.z-mu)*rstd*lnw[c0+6] + lnb[c0+6]);
        o[7] = f2b((a1.w-mu)*rstd*lnw[c0+7] + lnb[c0+7]);
        *(uint4*)&Ash[((size_t)(sub*4+i)*64 + lrow) * 8] = *(uint4*)o;
    }
    __syncthreads();

    f32x4 acc[4];
#pragma unroll
    for (int nt = 0; nt < 4; nt++) acc[nt] = (f32x4){0.f,0.f,0.f,0.f};
#pragma unroll
    for (int kk = 0; kk < 4; kk++) {
        bf16x8 af = *(const bf16x8*)&Ash[(((kk*4 + quad)*64) + wave*16 + l15) * 8];
#pragma unroll
        for (int nt = 0; nt < 4; nt++) {
            bf16x8 bfv = *(const bf16x8*)&Wsh[(((kk*4 + quad)*64) + nt*16 + l15) * 8];
            acc[nt] = __builtin_amdgcn_mfma_f32_16x16x32_bf16(af, bfv, acc[nt], 0, 0, 0);
        }
    }
#pragma unroll
    for (int nt = 0; nt < 4; nt++) {
        int n = bn + nt*16 + l15;
        if (n < EE) {
#pragma unroll
            for (int r = 0; r < 4; r++) {
                int m = bm + wave*16 + quad*4 + r;
                C[(size_t)m * EE + n] = acc[nt][r];
            }
        }
    }
}

// ================= conv + silu + dt/dA =================
__global__ __launch_bounds__(256) void convdt_kernel(const float* __restrict__ zx,
                                                     const float* __restrict__ cw,
                                                     const float* __restrict__ cb,
                                                     const float* __restrict__ dt_bias,
                                                     const float* __restrict__ A_log,
                                                     float* __restrict__ out,
                                                     float* __restrict__ dtb,
                                                     float* __restrict__ dab)
{
    int idx = blockIdx.x * 256 + threadIdx.x;     // over ML*CONVD
    int c = idx % CONVD;
    int bl = idx / CONVD;
    int l = bl & (LLEN - 1);
    const float* wr = cw + c * 4;
    const float* base = zx + (size_t)bl * EE + DI + c;  // xBC section
    float s = wr[3] * base[0];
    if (l >= 1) s = fmaf(wr[2], base[-(ptrdiff_t)EE], s);
    if (l >= 2) s = fmaf(wr[1], base[-(ptrdiff_t)(2*EE)], s);
    if (l >= 3) s = fmaf(wr[0], base[-(ptrdiff_t)(3*EE)], s);
    s += cb[c];
    out[idx] = siluf(s);

    if (idx < ML * NH) {
        int h = idx & 3;
        int row = idx >> 2;
        float v = zx[(size_t)row * EE + (EE - NH) + h] + dt_bias[h];
        float dt = (v > 20.f) ? v : log1pf(expf(v));
        dtb[idx] = dt;
        dab[idx] = expf(-expf(A_log[h]) * dt);
    }
}

// ================= Scan pass 1 (LDS-staged) =================
__global__ __launch_bounds__(64) void scan1(const float* __restrict__ conv,
                                            const float* __restrict__ dtb,
                                            const float* __restrict__ dab,
                                            float* __restrict__ seg,
                                            float* __restrict__ segsum)
{
    __shared__ float xs[TT*PP];
    __shared__ float Bsh[TT*NNs];
    __shared__ float dts[TT], das[TT];
    int bid = blockIdx.x;                 // (b*NH + h)*SEGS + s
    int s = bid % SEGS;
    int bh = bid / SEGS;
    int h = bh % NH;
    int b = bh / NH;
    int p = threadIdx.x;
    int row0 = b * LLEN + s * TT;
#pragma unroll 4
    for (int t = 0; t < TT; t++)
        xs[t*PP + p] = conv[(size_t)(row0 + t) * CONVD + h * PP + p];
#pragma unroll 4
    for (int tt = 0; tt < TT/2; tt++) {
        int t = tt*2 + (p >> 5);
        Bsh[t*NNs + (p & 31)] = conv[(size_t)(row0 + t) * CONVD + DI + (p & 31)];
    }
    if (p < TT) {
        dts[p] = dtb[(row0 + p) * NH + h];
        das[p] = dab[(row0 + p) * NH + h];
    }
    __syncthreads();

    float hreg[NNs];
#pragma unroll
    for (int n = 0; n < NNs; n++) hreg[n] = 0.f;
    float sdt = 0.f;
#pragma unroll 4
    for (int t = 0; t < TT; t++) {
        float dA = das[t];
        float dt = dts[t];
        float xv = xs[t*PP + p];
        float dtx = dt * xv;
#pragma unroll
        for (int n4 = 0; n4 < 8; n4++) {
            float4 Bv = *(const float4*)&Bsh[t*NNs + n4*4];
            hreg[n4*4+0] = fmaf(hreg[n4*4+0], dA, dtx * Bv.x);
            hreg[n4*4+1] = fmaf(hreg[n4*4+1], dA, dtx * Bv.y);
            hreg[n4*4+2] = fmaf(hreg[n4*4+2], dA, dtx * Bv.z);
            hreg[n4*4+3] = fmaf(hreg[n4*4+3], dA, dtx * Bv.w);
        }
        sdt += dt;
    }
    float* dst = seg + ((size_t)bid * PP + p) * NNs;
#pragma unroll
    for (int n4 = 0; n4 < 8; n4++)
        *(float4*)(dst + n4 * 4) = make_float4(hreg[n4*4+0], hreg[n4*4+1], hreg[n4*4+2], hreg[n4*4+3]);
    if (p == 0) segsum[bid] = sdt;
}

// ================= Scan pass 2: cross-segment combine (in-place) =================
__global__ __launch_bounds__(256) void scan2(float* __restrict__ seg,
                                             const float* __restrict__ segsum,
                                             const float* __restrict__ A_log)
{
    int bh = blockIdx.x >> 3;             // 0..BB*NH-1
    int chunk = blockIdx.x & 7;
    int h = bh % NH;
    int entry = chunk * 256 + threadIdx.x;   // 0..2047
    float negA = -expf(A_log[h]);
    float hs = 0.f;
    const float* ss = segsum + bh * SEGS;
    float* base = seg + (size_t)bh * SEGS * (PP * NNs) + entry;
    for (int j = 0; j < SEGS; j++) {
        float Aj = expf(negA * ss[j]);
        float e = base[(size_t)j * (PP * NNs)];
        base[(size_t)j * (PP * NNs)] = hs;
        hs = fmaf(Aj, hs, e);
    }
}

// ================= Scan pass 3 (LDS-staged), emit y =================
__global__ __launch_bounds__(64) void scan3(const float* __restrict__ conv,
                                            const float* __restrict__ dtb,
                                            const float* __restrict__ dab,
                                            const float* __restrict__ seg,
                                            const float* __restrict__ Dp,
                                            float* __restrict__ y)
{
    __shared__ float xs[TT*PP];
    __shared__ float Bsh[TT*NNs];
    __shared__ float Csh[TT*NNs];
    __shared__ float dts[TT], das[TT];
    int bid = blockIdx.x;
    int s = bid % SEGS;
    int bh = bid / SEGS;
    int h = bh % NH;
    int b = bh / NH;
    int p = threadIdx.x;
    int row0 = b * LLEN + s * TT;
#pragma unroll 4
    for (int t = 0; t < TT; t++)
        xs[t*PP + p] = conv[(size_t)(row0 + t) * CONVD + h * PP + p];
#pragma unroll 4
    for (int tt = 0; tt < TT/2; tt++) {
        int t = tt*2 + (p >> 5);
        Bsh[t*NNs + (p & 31)] = conv[(size_t)(row0 + t) * CONVD + DI + (p & 31)];
        Csh[t*NNs + (p & 31)] = conv[(size_t)(row0 + t) * CONVD + DI + NNs + (p & 31)];
    }
    if (p < TT) {
        dts[p] = dtb[(row0 + p) * NH + h];
        das[p] = dab[(row0 + p) * NH + h];
    }

    float hreg[NNs];
    const float* src = seg + ((size_t)bid * PP + p) * NNs;
#pragma unroll
    for (int n4 = 0; n4 < 8; n4++) {
        float4 v = *(const float4*)(src + n4 * 4);
        hreg[n4*4+0] = v.x; hreg[n4*4+1] = v.y; hreg[n4*4+2] = v.z; hreg[n4*4+3] = v.w;
    }
    float dp = Dp[h];
    __syncthreads();

#pragma unroll 4
    for (int t = 0; t < TT; t++) {
        float dA = das[t];
        float dt = dts[t];
        float xv = xs[t*PP + p];
        float dtx = dt * xv;
        float acc = 0.f;
#pragma unroll
        for (int n4 = 0; n4 < 8; n4++) {
            float4 Bv = *(const float4*)&Bsh[t*NNs + n4*4];
            float4 Cv = *(const float4*)&Csh[t*NNs + n4*4];
            hreg[n4*4+0] = fmaf(hreg[n4*4+0], dA, dtx * Bv.x);
            hreg[n4*4+1] = fmaf(hreg[n4*4+1], dA, dtx * Bv.y);
            hreg[n4*4+2] = fmaf(hreg[n4*4+2], dA, dtx * Bv.z);
            hreg[n4*4+3] = fmaf(hreg[n4*4+3], dA, dtx * Bv.w);
            acc = fmaf(hreg[n4*4+0], Cv.x, acc);
            acc = fmaf(hreg[n4*4+1], Cv.y, acc);
            acc = fmaf(hreg[n4*4+2], Cv.z, acc);
            acc = fmaf(hreg[n4*4+3], Cv.w, acc);
        }
        y[(size_t)(row0 + t) * DI + h * PP + p] = acc + dp * xv;
    }
}

// ================= Fused gated-RMSNorm + out_proj GEMM =================
// grid (2, ML/64); Xm[m][n] = resid[m][n] + r_m * ((y*silu(z)*rms_w) @ W^T)
__global__ __launch_bounds__(256) void grms_outproj_gemm(const float* __restrict__ Y,
                                                         const float* __restrict__ Z,   // bufBig (z = cols 0..255, stride EE)
                                                         const float* __restrict__ rmsw,
                                                         const u16* __restrict__ W,     // DD x DI bf16
                                                         const float* __restrict__ resid,
                                                         float* __restrict__ C)
{
    __shared__ __align__(16) u16 Ash[64*256];   // 32 KB
    __shared__ __align__(16) u16 Wsh[64*256];   // 32 KB
    __shared__ float red[64][4];
    __shared__ float rl[64];
    const int tid = threadIdx.x;
    const int wave = tid >> 6, lane = tid & 63;
    const int l15 = lane & 15, quad = lane >> 4;
    const int bm = blockIdx.y * 64;
    const int bn = blockIdx.x * 64;
    const int lrow = tid >> 2, sub = tid & 3;

    // stage W: 64 rows x 256 k
#pragma unroll
    for (int i = 0; i < 8; i++) {
        int k8 = sub + 4*i;
        uint4 wv = *(const uint4*)(W + (size_t)(bn + lrow) * DI + k8*8);
        *(uint4*)&Wsh[((size_t)k8*64 + lrow) * 8] = wv;
    }

    // gated prologue: row lrow, cols sub*64..+63
    const float* yr = Y + (size_t)(bm + lrow) * DI + sub*64;
    const float* zr = Z + (size_t)(bm + lrow) * EE + sub*64;
    float pq = 0.f;
#pragma unroll
    for (int i = 0; i < 8; i++) {          // chunks of 8 cols
        int c0 = sub*64 + i*8;
        float4 y0 = *(const float4*)(yr + i*8);
        float4 y1 = *(const float4*)(yr + i*8 + 4);
        float4 z0 = *(const float4*)(zr + i*8);
        float4 z1 = *(const float4*)(zr + i*8 + 4);
        float g[8];
        g[0] = y0.x * siluf(z0.x); g[1] = y0.y * siluf(z0.y);
        g[2] = y0.z * siluf(z0.z); g[3] = y0.w * siluf(z0.w);
        g[4] = y1.x * siluf(z1.x); g[5] = y1.y * siluf(z1.y);
        g[6] = y1.z * siluf(z1.z); g[7] = y1.w * siluf(z1.w);
        u16 o[8];
#pragma unroll
        for (int j = 0; j < 8; j++) {
            pq += g[j]*g[j];
            o[j] = f2b(g[j] * rmsw[c0 + j]);
        }
        *(uint4*)&Ash[((size_t)(sub*8 + i)*64 + lrow) * 8] = *(uint4*)o;
    }
    red[lrow][sub] = pq;
    __syncthreads();
    if (sub == 0) {
        float qq = red[lrow][0]+red[lrow][1]+red[lrow][2]+red[lrow][3];
        rl[lrow] = rsqrtf(qq * (1.f/DI) + 1e-5f);
    }
    __syncthreads();

    f32x4 acc[4];
#pragma unroll
    for (int nt = 0; nt < 4; nt++) acc[nt] = (f32x4){0.f,0.f,0.f,0.f};
#pragma unroll
    for (int kk = 0; kk < 8; kk++) {
        bf16x8 af = *(const bf16x8*)&Ash[(((kk*4 + quad)*64) + wave*16 + l15) * 8];
#pragma unroll
        for (int nt = 0; nt < 4; nt++) {
            bf16x8 bfv = *(const bf16x8*)&Wsh[(((kk*4 + quad)*64) + nt*16 + l15) * 8];
            acc[nt] = __builtin_amdgcn_mfma_f32_16x16x32_bf16(af, bfv, acc[nt], 0, 0, 0);
        }
    }
#pragma unroll
    for (int nt = 0; nt < 4; nt++) {
        int n = bn + nt*16 + l15;
#pragma unroll
        for (int r = 0; r < 4; r++) {
            int lm = wave*16 + quad*4 + r;
            int m = bm + lm;
            C[(size_t)m * DD + n] = acc[nt][r] * rl[lm] + resid[(size_t)m * DD + n];
        }
    }
}

// ================= Fused MLP: LN2 + fc1 + GLU + fc2 + residual =================
// grid ML/64 blocks; Out = Xm + (silu(x1)*x2) @ W2^T + b2, x12 = LN2(Xm) @ W1^T + b1
__global__ __launch_bounds__(256) void mlp_fused(const float* __restrict__ Xm,
                                                 const float* __restrict__ lnw,
                                                 const float* __restrict__ lnb,
                                                 const u16* __restrict__ W1,   // 512 x 128
                                                 const float* __restrict__ b1, // 512
                                                 const u16* __restrict__ W2,   // 128 x 256
                                                 const float* __restrict__ b2, // 128
                                                 float* __restrict__ Out)
{
    __shared__ __align__(16) u16 Ash[64*128];   // 16 KB
    __shared__ __align__(16) u16 Wsh[64*128];   // 16 KB
    __shared__ __align__(16) u16 Gsh[64*GPAD];  // 33 KB
    __shared__ float red[64][8];
    const int tid = threadIdx.x;
    const int wave = tid >> 6, lane = tid & 63;
    const int l15 = lane & 15, quad = lane >> 4;
    const int bm = blockIdx.x * 64;
    const int lrow = tid >> 2, sub = tid & 3;

    // LN2 prologue -> Ash (fragment-major, K=128)
    const float* xr = Xm + (size_t)(bm + lrow) * DD + sub*32;
    float4 xv[8];
    float ps = 0.f, pq = 0.f;
#pragma unroll
    for (int i = 0; i < 8; i++) {
        xv[i] = *(const float4*)(xr + i*4);
        ps += xv[i].x + xv[i].y + xv[i].z + xv[i].w;
        pq += xv[i].x*xv[i].x + xv[i].y*xv[i].y + xv[i].z*xv[i].z + xv[i].w*xv[i].w;
    }
    red[lrow][sub] = ps; red[lrow][4+sub] = pq;
    __syncthreads();
    float s = red[lrow][0]+red[lrow][1]+red[lrow][2]+red[lrow][3];
    float q = red[lrow][4]+red[lrow][5]+red[lrow][6]+red[lrow][7];
    float mu = s * (1.f/DD);
    float rstd = rsqrtf(q*(1.f/DD) - mu*mu + 1e-5f);
#pragma unroll
    for (int i = 0; i < 4; i++) {
        float4 a0 = xv[2*i], a1 = xv[2*i+1];
        int c0 = sub*32 + i*8;
        u16 o[8];
        o[0] = f2b((a0.x-mu)*rstd*lnw[c0+0] + lnb[c0+0]);
        o[1] = f2b((a0.y-mu)*rstd*lnw[c0+1] + lnb[c0+1]);
        o[2] = f2b((a0.z-mu)*rstd*lnw[c0+2] + lnb[c0+2]);
        o[3] = f2b((a0.w-mu)*rstd*lnw[c0+3] + lnb[c0+3]);
        o[4] = f2b((a1.x-mu)*rstd*lnw[c0+4] + lnb[c0+4]);
        o[5] = f2b((a1.y-mu)*rstd*lnw[c0+5] + lnb[c0+5]);
        o[6] = f2b((a1.z-mu)*rstd*lnw[c0+6] + lnb[c0+6]);
        o[7] = f2b((a1.w-mu)*rstd*lnw[c0+7] + lnb[c0+7]);
        *(uint4*)&Ash[((size_t)(sub*4+i)*64 + lrow) * 8] = *(uint4*)o;
    }
    __syncthreads();

    // cache A fragments (invariant across all fc1 tiles)
    bf16x8 afr[4];
#pragma unroll
    for (int kk = 0; kk < 4; kk++)
        afr[kk] = *(const bf16x8*)&Ash[(((kk*4 + quad)*64) + wave*16 + l15) * 8];

    // fc1 + GLU -> Gsh
    for (int p = 0; p < 4; p++) {
        f32x4 aa[4], bb[4];
        // x1 tile: W1 rows p*64..
        __syncthreads();
#pragma unroll
        for (int i = 0; i < 4; i++) {
            int k8 = sub + 4*i;
            uint4 wv = *(const uint4*)(W1 + (size_t)(p*64 + lrow) * DD + k8*8);
            *(uint4*)&Wsh[((size_t)k8*64 + lrow) * 8] = wv;
        }
        __syncthreads();
#pragma unroll
        for (int nt = 0; nt < 4; nt++) aa[nt] = (f32x4){0.f,0.f,0.f,0.f};
#pragma unroll
        for (int kk = 0; kk < 4; kk++) {
#pragma unroll
            for (int nt = 0; nt < 4; nt++) {
                bf16x8 bfv = *(const bf16x8*)&Wsh[(((kk*4 + quad)*64) + nt*16 + l15) * 8];
                aa[nt] = __builtin_amdgcn_mfma_f32_16x16x32_bf16(afr[kk], bfv, aa[nt], 0, 0, 0);
            }
        }
        // x2 tile: W1 rows 256 + p*64..
        __syncthreads();
#pragma unroll
        for (int i = 0; i < 4; i++) {
            int k8 = sub + 4*i;
            uint4 wv = *(const uint4*)(W1 + (size_t)(256 + p*64 + lrow) * DD + k8*8);
            *(uint4*)&Wsh[((size_t)k8*64 + lrow) * 8] = wv;
        }
        __syncthreads();
#pragma unroll
        for (int nt = 0; nt < 4; nt++) bb[nt] = (f32x4){0.f,0.f,0.f,0.f};
#pragma unroll
        for (int kk = 0; kk < 4; kk++) {
#pragma unroll
            for (int nt = 0; nt < 4; nt++) {
                bf16x8 bfv = *(const bf16x8*)&Wsh[(((kk*4 + quad)*64) + nt*16 + l15) * 8];
                bb[nt] = __builtin_amdgcn_mfma_f32_16x16x32_bf16(afr[kk], bfv, bb[nt], 0, 0, 0);
            }
        }
        // GLU -> Gsh (row-major bf16, padded)
#pragma unroll
        for (int nt = 0; nt < 4; nt++) {
            int n1 = p*64 + nt*16 + l15;
            float ba = b1[n1];
            float bbias = b1[256 + n1];
#pragma unroll
            for (int r = 0; r < 4; r++) {
                float a = aa[nt][r] + ba;
                float b = bb[nt][r] + bbias;
                int m = wave*16 + quad*4 + r;
                Gsh[m*GPAD + n1] = f2b(siluf(a) * b);
            }
        }
    }
    __syncthreads();

    // fc2: K=256 from Gsh, N=128
    f32x4 acc2[8];
#pragma unroll
    for (int i = 0; i < 8; i++) acc2[i] = (f32x4){0.f,0.f,0.f,0.f};
    for (int nh = 0; nh < 2; nh++) {
        for (int kh = 0; kh < 2; kh++) {
            __syncthreads();
#pragma unroll
            for (int i = 0; i < 4; i++) {
                int k8 = sub + 4*i;
                uint4 wv = *(const uint4*)(W2 + (size_t)(nh*64 + lrow) * DI + kh*128 + k8*8);
                *(uint4*)&Wsh[((size_t)k8*64 + lrow) * 8] = wv;
            }
            __syncthreads();
#pragma unroll
            for (int kk = 0; kk < 4; kk++) {
                bf16x8 af = *(const bf16x8*)&Gsh[(wave*16 + l15)*GPAD + kh*128 + kk*32 + quad*8];
#pragma unroll
                for (int nt = 0; nt < 4; nt++) {
                    bf16x8 bfv = *(const bf16x8*)&Wsh[(((kk*4 + quad)*64) + nt*16 + l15) * 8];
                    acc2[nh*4 + nt] = __builtin_amdgcn_mfma_f32_16x16x32_bf16(af, bfv, acc2[nh*4 + nt], 0, 0, 0);
                }
            }
        }
    }
    // epilogue: + b2 + residual
#pragma unroll
    for (int nh = 0; nh < 2; nh++) {
#pragma unroll
        for (int nt = 0; nt < 4; nt++) {
            int n = nh*64 + nt*16 + l15;
            float bv = b2[n];
#pragma unroll
            for (int r = 0; r < 4; r++) {
                int m = bm + wave*16 + quad*4 + r;
                Out[(size_t)m * DD + n] = acc2[nh*4 + nt][r] + bv + Xm[(size_t)m * DD + n];
            }
        }
    }
}

// ---------------- Final output copy (f32): [x ; residual] ----------------
__global__ __launch_bounds__(256) void outcopy_kernel(const float* __restrict__ x,
                                                      const float* __restrict__ xm,
                                                      float* __restrict__ out)
{
    int i = blockIdx.x * 256 + threadIdx.x;     // over ML*DD/4 granules
    float4 a = ((const float4*)x)[i];
    float4 b = ((const float4*)xm)[i];
    ((float4*)out)[i] = a;
    ((float4*)(out + (size_t)ML * DD))[i] = b;
}

extern "C" void kernel_launch(void* const* d_in, const int* in_sizes, int n_in,
                              void* d_out, int out_size, void* d_ws, size_t ws_size,
                              hipStream_t stream)
{
    (void)in_sizes; (void)n_in; (void)out_size; (void)ws_size;
    const float* x_in      = (const float*)d_in[0];
    const float* ln1_w     = (const float*)d_in[2];
    const float* ln1_b     = (const float*)d_in[3];
    const float* ln2_w     = (const float*)d_in[4];
    const float* ln2_b     = (const float*)d_in[5];
    const float* fc1_b     = (const float*)d_in[7];
    const float* fc2_b     = (const float*)d_in[9];
    const float* fc1_w     = (const float*)d_in[6];
    const float* fc2_w     = (const float*)d_in[8];
    const float* in_proj_w = (const float*)d_in[10];
    const float* conv_w    = (const float*)d_in[11];
    const float* conv_b    = (const float*)d_in[12];
    const float* dt_bias   = (const float*)d_in[13];
    const float* A_log     = (const float*)d_in[14];
    const float* Dp        = (const float*)d_in[15];
    const float* rms_w     = (const float*)d_in[16];
    const float* out_proj_w= (const float*)d_in[17];

    float* ws = (float*)d_ws;
    size_t o = 0;
    float* bufX    = ws + o; o += (size_t)ML * DD;       // f32
    float* bufXm   = ws + o; o += (size_t)ML * DD;       // f32
    float* bufY    = ws + o; o += (size_t)ML * DI;       // f32
    float* bufConv = ws + o; o += (size_t)ML * CONVD;    // f32
    float* bufDt   = ws + o; o += (size_t)ML * NH;
    float* bufDA   = ws + o; o += (size_t)ML * NH;
    float* bufSegA = ws + o; o += (size_t)BB * NH * SEGS;
    float* bufSeg  = ws + o; o += (size_t)BB * NH * SEGS * PP * NNs;  // 8.4 MB
    float* bufBig  = ws + o; o += (size_t)ML * EE;       // f32 zxbcdt
    u16* wIpH     = (u16*)(ws + o); o += (IPW_N + 1) / 2;
    u16* wOpH     = (u16*)(ws + o); o += (OPW_N + 1) / 2;
    u16* wF1H     = (u16*)(ws + o); o += (F1W_N + 1) / 2;
    u16* wF2H     = (u16*)(ws + o); o += (F2W_N + 1) / 2;

    hipMemcpyAsync(bufX, x_in, (size_t)ML * DD * sizeof(float),
                   hipMemcpyDeviceToDevice, stream);
    cvt_weights<<<CVT_TOT/256, 256, 0, stream>>>(in_proj_w, out_proj_w, fc1_w, fc2_w,
                                                 wIpH, wOpH, wF1H, wF2H);

    for (int i = 0; i < NBLK; i++) {
        const float* ln1wi = ln1_w + i * DD;
        const float* ln1bi = ln1_b + i * DD;
        const float* ln2wi = ln2_w + i * DD;
        const float* ln2bi = ln2_b + i * DD;
        const float* cwi   = conv_w + (size_t)i * CONVD * 4;
        const float* cbi   = conv_b + (size_t)i * CONVD;
        const float* dtbi  = dt_bias + i * NH;
        const float* ali   = A_log + i * NH;
        const float* dpi   = Dp + i * NH;
        const float* rwi   = rms_w + (size_t)i * DI;
        const float* f1bi  = fc1_b + (size_t)i * 512;
        const float* f2bi  = fc2_b + (size_t)i * DD;
        const u16* ipwi = wIpH + (size_t)i * EE * DD;
        const u16* opwi = wOpH + (size_t)i * DD * DI;
        const u16* f1wi = wF1H + (size_t)i * 512 * DD;
        const u16* f2wi = wF2H + (size_t)i * DD * DI;

        // zxbcdt = LN1(x) @ in_proj^T  (fused)
        inproj_ln_gemm<<<dim3(10, ML/64), 256, 0, stream>>>(bufX, ln1wi, ln1bi, ipwi, bufBig);
        // conv + silu + dt/dA
        convdt_kernel<<<(ML*CONVD)/256, 256, 0, stream>>>(bufBig, cwi, cbi, dtbi, ali,
                                                          bufConv, bufDt, bufDA);
        // selective scan (3 passes)
        scan1<<<BB*NH*SEGS, 64, 0, stream>>>(bufConv, bufDt, bufDA, bufSeg, bufSegA);
        scan2<<<BB*NH*8, 256, 0, stream>>>(bufSeg, bufSegA, ali);
        scan3<<<BB*NH*SEGS, 64, 0, stream>>>(bufConv, bufDt, bufDA, bufSeg, dpi, bufY);
        // x_m = x + gatedRMS(y,z) @ out_proj^T  (fused)
        grms_outproj_gemm<<<dim3(2, ML/64), 256, 0, stream>>>(bufY, bufBig, rwi, opwi,
                                                              bufX, bufXm);
        // x = x_m + MLP(LN2(x_m))  (fully fused)
        mlp_fused<<<ML/64, 256, 0, stream>>>(bufXm, ln2wi, ln2bi, f1wi, f1bi,
                                             f2wi, f2bi, bufX);
    }

    outcopy_kernel<<<(ML*DD)/1024, 256, 0, stream>>>(bufX, bufXm, (float*)d_out);
}